// Round 3
// baseline (542.405 us; speedup 1.0000x reference)
//
#include <hip/hip_runtime.h>
#include <stdint.h>

// XLA emits multiply and add as separate uncontracted HLOs; HIP's default
// -ffp-contract=fast would fuse them into fma and break bit-exact RNG/score
// reproduction. Kill contraction globally.
#pragma clang fp contract(off)

struct Keys { uint32_t k[12]; };  // [dir(2)][rs-step(3)][2 words]

// ---- Threefry-2x32, 20 rounds, exact JAX schedule ----
__host__ __device__ inline void tf2x32(uint32_t k0, uint32_t k1,
                                       uint32_t x0, uint32_t x1,
                                       uint32_t* o0, uint32_t* o1) {
  const uint32_t ks2 = k0 ^ k1 ^ 0x1BD11BDAu;
  x0 += k0; x1 += k1;
#define TF_R(r) { x0 += x1; x1 = (x1 << (r)) | (x1 >> (32 - (r))); x1 ^= x0; }
  TF_R(13) TF_R(15) TF_R(26) TF_R(6)
  x0 += k1;  x1 += ks2 + 1u;
  TF_R(17) TF_R(29) TF_R(16) TF_R(24)
  x0 += ks2; x1 += k0 + 2u;
  TF_R(13) TF_R(15) TF_R(26) TF_R(6)
  x0 += k0;  x1 += k1 + 3u;
  TF_R(17) TF_R(29) TF_R(16) TF_R(24)
  x0 += k1;  x1 += ks2 + 4u;
  TF_R(13) TF_R(15) TF_R(26) TF_R(6)
  x0 += ks2; x1 += k0 + 5u;
#undef TF_R
  *o0 = x0; *o1 = x1;
}

// ---- XLA ErfInv32 (Giles coefficients, exact op order) ----
__device__ inline float erfinv_xla(float x) {
#pragma clang fp contract(off)
  float w = -log1pf(-(x * x));
  float p;
  if (w < 5.0f) {
    w = w - 2.5f;
    p = 2.81022636e-08f;
    p = 3.43273939e-07f  + p * w;
    p = -3.5233877e-06f  + p * w;
    p = -4.39150654e-06f + p * w;
    p = 0.00021858087f   + p * w;
    p = -0.00125372503f  + p * w;
    p = -0.00417768164f  + p * w;
    p = 0.246640727f     + p * w;
    p = 1.50140941f      + p * w;
  } else {
    w = sqrtf(w) - 3.0f;
    p = -0.000200214257f;
    p = 0.000100950558f  + p * w;
    p = 0.00134934322f   + p * w;
    p = -0.00367342844f  + p * w;
    p = 0.00573950773f   + p * w;
    p = -0.0076224613f   + p * w;
    p = 0.00943887047f   + p * w;
    p = 1.00167406f      + p * w;
    p = 2.83297682f      + p * w;
  }
  return p * x;
}

// jax.random.normal element `idx` under key (k0,k1), partitionable stream.
__device__ inline float jax_normal(uint32_t k0, uint32_t k1, uint32_t idx) {
#pragma clang fp contract(off)
  uint32_t o0, o1;
  tf2x32(k0, k1, 0u, idx, &o0, &o1);
  uint32_t bits = o0 ^ o1;
  float f = __uint_as_float((bits >> 9) | 0x3f800000u) - 1.0f;
  float u = f * 2.0f + (-0x1.fffffep-1f);
  u = fmaxf(-0x1.fffffep-1f, u);
  return 0x1.6a09e6p+0f * erfinv_xla(u);  // float(sqrt(2)) * erfinv(u)
}

// Bilinear corr score; association matches XLA: ((t00+t01)+t10)+t11.
__device__ inline float score_at(const float* __restrict__ base, int stride,
                                 float x, float y) {
#pragma clang fp contract(off)
  float x0 = floorf(x), y0 = floorf(y);
  float wx = x - x0, wy = y - y0;
  int xi = (int)x0; xi = xi < 0 ? 0 : (xi > 63 ? 63 : xi);
  int yi = (int)y0; yi = yi < 0 ? 0 : (yi > 63 ? 63 : yi);
  int x1 = xi + 1 > 63 ? 63 : xi + 1;
  int y1 = yi + 1 > 63 ? 63 : yi + 1;
  float v00 = base[(yi * 64 + xi) * stride];
  float v01 = base[(yi * 64 + x1) * stride];
  float v10 = base[(y1 * 64 + xi) * stride];
  float v11 = base[(y1 * 64 + x1) * stride];
  float omx = 1.0f - wx, omy = 1.0f - wy;
  return (((v00 * omx) * omy + (v01 * wx) * omy) + (v10 * omx) * wy) + (v11 * wx) * wy;
}

// Agent-scope 8B coord exchange: bypasses L1/L2, so cross-XCD reads after the
// grid barrier can never see stale cached lines (G16-safe by construction).
__device__ __forceinline__ void st_coord(float2* buf, int idx, float2 v) {
  unsigned long long u; __builtin_memcpy(&u, &v, 8);
  __hip_atomic_store((unsigned long long*)(buf + idx), u,
                     __ATOMIC_RELAXED, __HIP_MEMORY_SCOPE_AGENT);
}
__device__ __forceinline__ float2 ld_coord(const float2* buf, int idx) {
  unsigned long long u = __hip_atomic_load((const unsigned long long*)(buf + idx),
                                           __ATOMIC_RELAXED, __HIP_MEMORY_SCOPE_AGENT);
  float2 v; __builtin_memcpy(&v, &u, 8); return v;
}

// Grid barrier, one counter slot per phase (no reset/wraparound). Counters are
// zeroed by a captured hipMemsetAsync before launch. All 512 blocks (64 thr,
// 0 LDS, ~80 VGPR) are trivially co-resident on 256 CUs.
__device__ __forceinline__ void grid_barrier(uint32_t* bar, int slot, uint32_t nblk) {
  __syncthreads();
  if (threadIdx.x == 0) {
    __threadfence();                       // release own stores device-wide
    atomicAdd(&bar[slot], 1u);             // device-scope arrive
    while (__hip_atomic_load(&bar[slot], __ATOMIC_RELAXED,
                             __HIP_MEMORY_SCOPE_AGENT) < nblk)
      __builtin_amdgcn_s_sleep(1);
    __threadfence();                       // acquire
  }
  __syncthreads();
}

// Propagate candidates from neighbor coords (read via agent-scope loads).
__device__ __forceinline__ void prop(const float2* buf, int gbase, int i, int j,
                                     int dx, int dy, const float* __restrict__ base,
                                     int stride, float2& bst, float& bs) {
#pragma clang fp contract(off)
  int jh = (j - dx) & 63;                  // roll along W
  int iv = (i - dy) & 63;                  // roll along H
  float2 ch = ld_coord(buf, gbase + ((i << 6) | jh));
  float2 cv = ld_coord(buf, gbase + ((iv << 6) | j));
  ch.x = fminf(fmaxf(ch.x + (float)dx, 0.0f), 63.0f);
  cv.y = fminf(fmaxf(cv.y + (float)dy, 0.0f), 63.0f);
  float sh = score_at(base, stride, ch.x, ch.y);
  float sv = score_at(base, stride, cv.x, cv.y);
  if (sh > bs) bst = ch;                   // upd = s > best_s
  bs = fmaxf(sh, bs);
  if (sv > bs) bst = cv;
  bs = fmaxf(sv, bs);
}

// Random search. Carried bs is bit-identical to the reference's recomputed
// old score (same pure function of the same coords).
__device__ __forceinline__ void rs(const float* __restrict__ base, int stride,
                                   float n0, float n1, float2& bst, float& bs) {
#pragma clang fp contract(off)
  float nx = fminf(fmaxf(bst.x + 3.0f * n0, 0.0f), 63.0f);
  float ny = fminf(fmaxf(bst.y + 3.0f * n1, 0.0f), 63.0f);
  float sn = score_at(base, stride, nx, ny);
  if (sn - bs > 0.0f) { bst = make_float2(nx, ny); bs = sn; }
}

__global__ __launch_bounds__(64) void pm_all(
    const float* __restrict__ mf, const float* __restrict__ mb,
    const float* __restrict__ corr, float* __restrict__ out,
    float2* bufA, float2* bufB, uint32_t* bar, Keys keys) {
#pragma clang fp contract(off)
  const int g = (int)(blockIdx.x * 64 + threadIdx.x);   // 0..32767
  const int dir = g >> 14, b = (g >> 12) & 3, p = g & 4095;
  const int i = p >> 6, j = p & 63;
  const int gbase = g & ~4095;
  const uint32_t nblk = gridDim.x;

  const float* base; int stride;
  if (dir == 0) { base = corr + (size_t)(b * 4096 + p) * 4096; stride = 1; }
  else          { base = corr + (size_t)b * 16777216 + p;      stride = 4096; }

  // All 6 normals up front: pure fn of (key, idx); ALU overlaps first gathers.
  const uint32_t* kk = &keys.k[dir * 6];
  const uint32_t pg = (uint32_t)(b * 4096 + p);
  float n[6];
  for (int s = 0; s < 3; ++s) {
    n[2 * s]     = jax_normal(kk[2 * s], kk[2 * s + 1], 2u * pg);
    n[2 * s + 1] = jax_normal(kk[2 * s], kk[2 * s + 1], 2u * pg + 1u);
  }

  // ---- step 1: propagate(+1,+1) from matching, + rs(k1) ----
  const float* m = dir ? mb : mf;
  int jh = (j - 1) & 63, iv = (i - 1) & 63;
  float2 c  = make_float2(m[((b * 2 + 0) * 64 + i ) * 64 + j ], m[((b * 2 + 1) * 64 + i ) * 64 + j ]);
  float2 ch = make_float2(m[((b * 2 + 0) * 64 + i ) * 64 + jh], m[((b * 2 + 1) * 64 + i ) * 64 + jh]);
  float2 cv = make_float2(m[((b * 2 + 0) * 64 + iv) * 64 + j ], m[((b * 2 + 1) * 64 + iv) * 64 + j ]);
  ch.x = fminf(fmaxf(ch.x + 1.0f, 0.0f), 63.0f);
  cv.y = fminf(fmaxf(cv.y + 1.0f, 0.0f), 63.0f);
  float s0 = score_at(base, stride, c.x,  c.y);
  float sh = score_at(base, stride, ch.x, ch.y);
  float sv = score_at(base, stride, cv.x, cv.y);
  float2 bst = c; float bs = s0;
  if (sh > bs) bst = ch;
  bs = fmaxf(sh, bs);
  if (sv > bs) bst = cv;
  bs = fmaxf(sv, bs);
  rs(base, stride, n[0], n[1], bst, bs);
  st_coord(bufA, g, bst);
  grid_barrier(bar, 0, nblk);

  // ---- step 2: propagate(-1,-1) + rs(k2) ----
  prop(bufA, gbase, i, j, -1, -1, base, stride, bst, bs);
  rs(base, stride, n[2], n[3], bst, bs);
  st_coord(bufB, g, bst);
  grid_barrier(bar, 1, nblk);

  // ---- step 3: propagate(-1,+1) + rs(k3) ----
  prop(bufB, gbase, i, j, -1, 1, base, stride, bst, bs);
  rs(base, stride, n[4], n[5], bst, bs);
  st_coord(bufA, g, bst);
  grid_barrier(bar, 2, nblk);

  // ---- step 4: propagate(+1,-1), no rs; only res_b needed downstream ----
  prop(bufA, gbase, i, j, 1, -1, base, stride, bst, bs);
  if (dir == 1) st_coord(bufB, g, bst);
  grid_barrier(bar, 3, nblk);

  // ---- combine: bilinear-sample res_b at rf, fwd-bwd check, transpose out ----
  if (dir == 0) {
    float2 rf = bst;
    const int rbb = 16384 + b * 4096;
    float x0 = floorf(rf.x), y0 = floorf(rf.y);
    float wx = rf.x - x0, wy = rf.y - y0;
    int xi = (int)x0; xi = xi < 0 ? 0 : (xi > 63 ? 63 : xi);
    int yi = (int)y0; yi = yi < 0 ? 0 : (yi > 63 ? 63 : yi);
    int x1 = xi + 1 > 63 ? 63 : xi + 1;
    int y1 = yi + 1 > 63 ? 63 : yi + 1;
    float2 v00 = ld_coord(bufB, rbb + yi * 64 + xi);
    float2 v01 = ld_coord(bufB, rbb + yi * 64 + x1);
    float2 v10 = ld_coord(bufB, rbb + y1 * 64 + xi);
    float2 v11 = ld_coord(bufB, rbb + y1 * 64 + x1);
    float omx = 1.0f - wx, omy = 1.0f - wy;
    float c0 = (((v00.x * omx) * omy + (v01.x * wx) * omy) + (v10.x * omx) * wy) + (v11.x * wx) * wy;
    float c1 = (((v00.y * omx) * omy + (v01.y * wx) * omy) + (v10.y * omx) * wy) + (v11.y * wx) * wy;
    float d = fmaxf(fabsf(rf.x - c0), fabsf(rf.y - c1));
    bool invalid = d > 0.01f;
    out[((b * 2 + 0) * 64 + i) * 64 + j] = invalid ? mf[((b * 2 + 0) * 64 + i) * 64 + j] : rf.x;
    out[((b * 2 + 1) * 64 + i) * 64 + j] = invalid ? mf[((b * 2 + 1) * 64 + i) * 64 + j] : rf.y;
  }
}

extern "C" void kernel_launch(void* const* d_in, const int* in_sizes, int n_in,
                              void* d_out, int out_size, void* d_ws, size_t ws_size,
                              hipStream_t stream) {
  const float* mf   = (const float*)d_in[0];
  const float* mb   = (const float*)d_in[1];
  const float* corr = (const float*)d_in[2];
  float* out = (float*)d_out;

  uint32_t* bar = (uint32_t*)d_ws;                       // 4 barrier slots
  float2* bufA  = (float2*)((char*)d_ws + 256);          // 256 KB
  float2* bufB  = bufA + 32768;                          // 256 KB

  // Host-side key derivation from seed 42 -> root key (0, 42).
  // split(root,2)[d] = enc_root(0, d); split(k,3)[s] = enc_k(0, s).
  Keys K;
  uint32_t kf0, kf1, kb0, kb1;
  tf2x32(0u, 42u, 0u, 0u, &kf0, &kf1);
  tf2x32(0u, 42u, 0u, 1u, &kb0, &kb1);
  for (uint32_t s = 0; s < 3; ++s) {
    tf2x32(kf0, kf1, 0u, s, &K.k[0 + s * 2], &K.k[0 + s * 2 + 1]);
    tf2x32(kb0, kb1, 0u, s, &K.k[6 + s * 2], &K.k[6 + s * 2 + 1]);
  }

  // ws is poisoned 0xAA before every timed launch: zero the barrier slots.
  hipMemsetAsync(d_ws, 0, 256, stream);
  pm_all<<<dim3(512), dim3(64), 0, stream>>>(mf, mb, corr, out, bufA, bufB, bar, K);
  (void)in_sizes; (void)n_in; (void)out_size; (void)ws_size;
}

// Round 4
// 333.539 us; speedup vs baseline: 1.6262x; 1.6262x over previous
//
#include <hip/hip_runtime.h>
#include <stdint.h>

// XLA emits multiply and add as separate uncontracted HLOs; HIP's default
// -ffp-contract=fast would fuse them into fma and break bit-exact RNG/score
// reproduction. Kill contraction globally.
#pragma clang fp contract(off)

// ---- Threefry-2x32, 20 rounds, exact JAX schedule ----
__host__ __device__ inline void tf2x32(uint32_t k0, uint32_t k1,
                                       uint32_t x0, uint32_t x1,
                                       uint32_t* o0, uint32_t* o1) {
  const uint32_t ks2 = k0 ^ k1 ^ 0x1BD11BDAu;
  x0 += k0; x1 += k1;
#define TF_R(r) { x0 += x1; x1 = (x1 << (r)) | (x1 >> (32 - (r))); x1 ^= x0; }
  TF_R(13) TF_R(15) TF_R(26) TF_R(6)
  x0 += k1;  x1 += ks2 + 1u;
  TF_R(17) TF_R(29) TF_R(16) TF_R(24)
  x0 += ks2; x1 += k0 + 2u;
  TF_R(13) TF_R(15) TF_R(26) TF_R(6)
  x0 += k0;  x1 += k1 + 3u;
  TF_R(17) TF_R(29) TF_R(16) TF_R(24)
  x0 += k1;  x1 += ks2 + 4u;
  TF_R(13) TF_R(15) TF_R(26) TF_R(6)
  x0 += ks2; x1 += k0 + 5u;
#undef TF_R
  *o0 = x0; *o1 = x1;
}

// ---- XLA ErfInv32 (Giles coefficients, exact op order) ----
__device__ inline float erfinv_xla(float x) {
#pragma clang fp contract(off)
  float w = -log1pf(-(x * x));
  float p;
  if (w < 5.0f) {
    w = w - 2.5f;
    p = 2.81022636e-08f;
    p = 3.43273939e-07f  + p * w;
    p = -3.5233877e-06f  + p * w;
    p = -4.39150654e-06f + p * w;
    p = 0.00021858087f   + p * w;
    p = -0.00125372503f  + p * w;
    p = -0.00417768164f  + p * w;
    p = 0.246640727f     + p * w;
    p = 1.50140941f      + p * w;
  } else {
    w = sqrtf(w) - 3.0f;
    p = -0.000200214257f;
    p = 0.000100950558f  + p * w;
    p = 0.00134934322f   + p * w;
    p = -0.00367342844f  + p * w;
    p = 0.00573950773f   + p * w;
    p = -0.0076224613f   + p * w;
    p = 0.00943887047f   + p * w;
    p = 1.00167406f      + p * w;
    p = 2.83297682f      + p * w;
  }
  return p * x;
}

// jax.random.normal element `idx` under key (k0,k1), partitionable stream.
__device__ inline float jax_normal(uint32_t k0, uint32_t k1, uint32_t idx) {
#pragma clang fp contract(off)
  uint32_t o0, o1;
  tf2x32(k0, k1, 0u, idx, &o0, &o1);
  uint32_t bits = o0 ^ o1;
  float f = __uint_as_float((bits >> 9) | 0x3f800000u) - 1.0f;
  float u = f * 2.0f + (-0x1.fffffep-1f);
  u = fmaxf(-0x1.fffffep-1f, u);
  return 0x1.6a09e6p+0f * erfinv_xla(u);  // float(sqrt(2)) * erfinv(u)
}

// Bilinear corr score; association matches XLA: ((t00+t01)+t10)+t11.
__device__ inline float score_at(const float* __restrict__ base, int stride,
                                 float x, float y) {
#pragma clang fp contract(off)
  float x0 = floorf(x), y0 = floorf(y);
  float wx = x - x0, wy = y - y0;
  int xi = (int)x0; xi = xi < 0 ? 0 : (xi > 63 ? 63 : xi);
  int yi = (int)y0; yi = yi < 0 ? 0 : (yi > 63 ? 63 : yi);
  int x1 = xi + 1 > 63 ? 63 : xi + 1;
  int y1 = yi + 1 > 63 ? 63 : yi + 1;
  float v00 = base[(yi * 64 + xi) * stride];
  float v01 = base[(yi * 64 + x1) * stride];
  float v10 = base[(y1 * 64 + xi) * stride];
  float v11 = base[(y1 * 64 + x1) * stride];
  float omx = 1.0f - wx, omy = 1.0f - wy;
  return (((v00 * omx) * omy + (v01 * wx) * omy) + (v10 * omx) * wy) + (v11 * wx) * wy;
}

// Fused propagate(+optional random-search) step. One pixel per thread,
// 512 blocks x 64 threads -> all 256 CUs active. Kernel-launch boundary is
// the global barrier between steps (R3 showed a sw fabric barrier costs
// ~65 us/phase at 512 blocks; launch boundaries are far cheaper).
// Buffer entry = (x, y, score, unused): carried score is bit-identical to the
// reference's per-step recompute (always exactly score_at(coord), same pure
// function / op order), so steps 2-4 skip the own-pixel score gathers.
__global__ __launch_bounds__(64) void step_kernel(
    const float* __restrict__ mf, const float* __restrict__ mb,
    const float4* __restrict__ in_c, float4* __restrict__ out_c,
    const float* __restrict__ corr, int dx, int dy,
    uint32_t k0f, uint32_t k1f, uint32_t k0b, uint32_t k1b,
    int do_rs, int from_matching) {
#pragma clang fp contract(off)
  int g = (int)(blockIdx.x * 64 + threadIdx.x);   // 0..32767
  int dir = g >> 14, b = (g >> 12) & 3, p = g & 4095;
  int i = p >> 6, j = p & 63;

  const float* base; int stride;
  if (dir == 0) { base = corr + (size_t)(b * 4096 + p) * 4096; stride = 1; }
  else          { base = corr + (size_t)b * 16777216 + p;      stride = 4096; }

  int jh = (j - dx) & 63;            // roll along W
  int iv = (i - dy) & 63;            // roll along H

  float2 bst; float bs;
  float2 ch, cv;
  if (from_matching) {
    const float* m = dir ? mb : mf;
    float2 c = make_float2(m[((b * 2 + 0) * 64 + i) * 64 + j],
                           m[((b * 2 + 1) * 64 + i) * 64 + j]);
    ch = make_float2(m[((b * 2 + 0) * 64 + i ) * 64 + jh], m[((b * 2 + 1) * 64 + i ) * 64 + jh]);
    cv = make_float2(m[((b * 2 + 0) * 64 + iv) * 64 + j ], m[((b * 2 + 1) * 64 + iv) * 64 + j ]);
    bst = c;
    bs = score_at(base, stride, c.x, c.y);
  } else {
    const float4* ic = in_c + dir * 16384 + b * 4096;
    float4 own = ic[p];
    float4 nh  = ic[(i << 6) | jh];
    float4 nv  = ic[(iv << 6) | j];
    bst = make_float2(own.x, own.y);
    bs  = own.z;                      // == score_at(own.xy), bit-exact
    ch = make_float2(nh.x, nh.y);
    cv = make_float2(nv.x, nv.y);
  }
  ch.x = fminf(fmaxf(ch.x + (float)dx, 0.0f), 63.0f);  // + [dx,0], clamp
  cv.y = fminf(fmaxf(cv.y + (float)dy, 0.0f), 63.0f);  // + [0,dy], clamp

  float sh = score_at(base, stride, ch.x, ch.y);
  float sv = score_at(base, stride, cv.x, cv.y);
  if (sh > bs) bst = ch;                // upd = s > best_s
  bs = fmaxf(sh, bs);
  if (sv > bs) bst = cv;
  bs = fmaxf(sv, bs);

  if (do_rs) {
    uint32_t kk0 = dir ? k0b : k0f, kk1 = dir ? k1b : k1f;
    uint32_t pg = (uint32_t)(b * 4096 + p);        // flat (b,i,j) over (4,64,64)
    float n0 = jax_normal(kk0, kk1, 2u * pg);
    float n1 = jax_normal(kk0, kk1, 2u * pg + 1u);
    float nx = fminf(fmaxf(bst.x + 3.0f * n0, 0.0f), 63.0f);
    float ny = fminf(fmaxf(bst.y + 3.0f * n1, 0.0f), 63.0f);
    float sn = score_at(base, stride, nx, ny);
    if (sn - bs > 0.0f) { bst = make_float2(nx, ny); bs = sn; }  // new_s - 1.0*old_s > 0
  }
  out_c[dir * 16384 + b * 4096 + p] = make_float4(bst.x, bst.y, bs, 0.0f);
}

// Bilinear-sample res_b at res_f, fwd-bwd consistency, transpose to (B,2,H,W).
__global__ __launch_bounds__(256) void combine_kernel(const float* __restrict__ mf,
                                                      const float4* __restrict__ res,
                                                      float* __restrict__ out) {
#pragma clang fp contract(off)
  int pg = (int)(blockIdx.x * 256 + threadIdx.x);   // 0..16383
  int b = pg >> 12, hw = pg & 4095;
  int i = hw >> 6, j = hw & 63;
  float4 rf4 = res[pg];
  float2 rf = make_float2(rf4.x, rf4.y);
  const float4* rb = res + 16384 + b * 4096;
  float x0 = floorf(rf.x), y0 = floorf(rf.y);
  float wx = rf.x - x0, wy = rf.y - y0;
  int xi = (int)x0; xi = xi < 0 ? 0 : (xi > 63 ? 63 : xi);
  int yi = (int)y0; yi = yi < 0 ? 0 : (yi > 63 ? 63 : yi);
  int x1 = xi + 1 > 63 ? 63 : xi + 1;
  int y1 = yi + 1 > 63 ? 63 : yi + 1;
  float4 v00 = rb[yi * 64 + xi], v01 = rb[yi * 64 + x1];
  float4 v10 = rb[y1 * 64 + xi], v11 = rb[y1 * 64 + x1];
  float omx = 1.0f - wx, omy = 1.0f - wy;
  float c0 = (((v00.x * omx) * omy + (v01.x * wx) * omy) + (v10.x * omx) * wy) + (v11.x * wx) * wy;
  float c1 = (((v00.y * omx) * omy + (v01.y * wx) * omy) + (v10.y * omx) * wy) + (v11.y * wx) * wy;
  float d = fmaxf(fabsf(rf.x - c0), fabsf(rf.y - c1));
  bool invalid = d > 0.01f;
  out[((b * 2 + 0) * 64 + i) * 64 + j] = invalid ? mf[((b * 2 + 0) * 64 + i) * 64 + j] : rf.x;
  out[((b * 2 + 1) * 64 + i) * 64 + j] = invalid ? mf[((b * 2 + 1) * 64 + i) * 64 + j] : rf.y;
}

extern "C" void kernel_launch(void* const* d_in, const int* in_sizes, int n_in,
                              void* d_out, int out_size, void* d_ws, size_t ws_size,
                              hipStream_t stream) {
  const float* mf   = (const float*)d_in[0];
  const float* mb   = (const float*)d_in[1];
  const float* corr = (const float*)d_in[2];
  float* out  = (float*)d_out;
  float4* bufA = (float4*)d_ws;             // [2][4][4096] float4 = 512 KB
  float4* bufB = bufA + 32768;              // second 512 KB

  // Host-side key derivation from seed 42 -> root key (0, 42).
  // split(root,2)[d] = enc_root(0, d); split(k,3)[s] = enc_k(0, s).
  uint32_t kf0, kf1, kb0, kb1, K[12];
  tf2x32(0u, 42u, 0u, 0u, &kf0, &kf1);
  tf2x32(0u, 42u, 0u, 1u, &kb0, &kb1);
  for (uint32_t s = 0; s < 3; ++s) {
    tf2x32(kf0, kf1, 0u, s, &K[0 + s * 2], &K[0 + s * 2 + 1]);
    tf2x32(kb0, kb1, 0u, s, &K[6 + s * 2], &K[6 + s * 2 + 1]);
  }

  dim3 grid(512), block(64);
  // step 1: propagate(+1,+1) from matching, + random_search(k1)
  step_kernel<<<grid, block, 0, stream>>>(mf, mb, nullptr, bufA, corr,  1,  1,
                                          K[0], K[1], K[6], K[7], 1, 1);
  // step 2: propagate(-1,-1), + random_search(k2)
  step_kernel<<<grid, block, 0, stream>>>(mf, mb, bufA, bufB, corr, -1, -1,
                                          K[2], K[3], K[8], K[9], 1, 0);
  // step 3: propagate(-1,+1), + random_search(k3)
  step_kernel<<<grid, block, 0, stream>>>(mf, mb, bufB, bufA, corr, -1,  1,
                                          K[4], K[5], K[10], K[11], 1, 0);
  // step 4: propagate(+1,-1), no rs
  step_kernel<<<grid, block, 0, stream>>>(mf, mb, bufA, bufB, corr,  1, -1,
                                          0u, 0u, 0u, 0u, 0, 0);
  combine_kernel<<<dim3(64), dim3(256), 0, stream>>>(mf, bufB, out);
  (void)in_sizes; (void)n_in; (void)out_size; (void)ws_size;
}